// Round 20
// baseline (300.512 us; speedup 1.0000x reference)
//
#include <hip/hip_runtime.h>
#include <hip/hip_bf16.h>

// CPSFMemcellAutoencoder: B=8, 256x256 input, N=16, S=128, M=32, T=131072.
// Workspace layout (~260 MB):
//   [0, 67108864)             a_s8  : fp8 [8b][8 cg16][65536 hw][16 ci]
//     REUSED: t64 at [0, 33554432)  : POS-MAJOR [16 pos][131072 tok][4] f32
//   dec1 at [67108864, 73400320)    : [8,3,256,256] f32
//   [134217728, 167772160)    t_star: [T,128] bf16 token-major
//   [201326592, +33554432)    a_n   : [8,16,256,256] BF16 (n-branch, R20: halved)
//     REUSED: wt8  at +201326592 (147456 B conv2_s weights fp8 chunk-major)
//     REUSED: part at +201850880 (1024 x 5120 f32 partials)
//     REUSED: Emat at +224000000 (32*64 f32)
//   [243269632, 260046848)    wmat  : [T,32] f32  (written by conv2n_fused)
//   [260046848, 260050944)    WtW / [260050944, 260067328) WtT / [260067328, ...) cvn
//
// R20: (1) a_n bf16 (halves conv1n write + conv2n's stride-2-amplified read);
//      (2) conv2s K=128 per barrier-pair (18 -> 9 pairs/block, spill rule kept).
// conv1s FROZEN at ~50us (VALU+write structural floor; 2 neutral attempts).

#define ALPHA_F 1e-6f
#define TTOT 131072

typedef __attribute__((ext_vector_type(8))) short bf16x8;
typedef __attribute__((ext_vector_type(4))) float f32x4;

__device__ __forceinline__ float silu_f(float x) {
    return x * __builtin_amdgcn_rcpf(1.f + __expf(-x));
}

__device__ __forceinline__ short f2bf(float f) {
    __hip_bfloat16 h = __float2bfloat16(f);
    union { __hip_bfloat16 b; short s; } u; u.b = h; return u.s;
}

__device__ __forceinline__ float bf2f(unsigned short s) {
    union { unsigned u; float f; } c; c.u = (unsigned)s << 16; return c.f;
}

__device__ __forceinline__ int pack_fp8x4(float a, float b, float c, float d) {
    int lo = __builtin_amdgcn_cvt_pk_fp8_f32(a, b, 0, false);
    return  __builtin_amdgcn_cvt_pk_fp8_f32(c, d, lo, true);
}

// ---------------- decoder final conv 3x3, Cin=3, CO=3, f32 out ----------------
template<int CO>
__global__ __launch_bounds__(256) void conv1_silu(
    const float* __restrict__ x, const float* __restrict__ wgt,
    const float* __restrict__ bias, float* __restrict__ out)
{
    int idx = blockIdx.x * 256 + threadIdx.x;      // (b,h,w)
    int w = idx & 255, h = (idx >> 8) & 255, b = idx >> 16;
    const float* xb = x + (size_t)b * 3 * 65536;
    float in[27];
#pragma unroll
    for (int ci = 0; ci < 3; ci++)
#pragma unroll
        for (int ky = 0; ky < 3; ky++)
#pragma unroll
            for (int kx = 0; kx < 3; kx++) {
                int hh = h + ky - 1, ww = w + kx - 1;
                bool ok = ((unsigned)hh < 256u) && ((unsigned)ww < 256u);
                in[(ci * 3 + ky) * 3 + kx] = ok ? xb[(ci << 16) + (hh << 8) + ww] : 0.f;
            }
    float* ob = out + (size_t)b * CO * 65536 + (h << 8) + w;
#pragma unroll 4
    for (int co = 0; co < CO; co++) {
        float acc = bias[co];          // uniform index -> s_load
#pragma unroll
        for (int k = 0; k < 27; k++) acc += in[k] * wgt[co * 27 + k];
        ob[(size_t)co << 16] = silu_f(acc);
    }
}

// ---------------- n-branch conv1: 3->16, NCHW BF16 out (R20) ----------------
__global__ __launch_bounds__(256) void conv1n_kern(
    const float* __restrict__ x, const float* __restrict__ wgt,
    const float* __restrict__ bias, __hip_bfloat16* __restrict__ out)
{
    int idx = blockIdx.x * 256 + threadIdx.x;      // (b,h,w)
    int w = idx & 255, h = (idx >> 8) & 255, b = idx >> 16;
    const float* xb = x + (size_t)b * 3 * 65536;
    float in[27];
#pragma unroll
    for (int ci = 0; ci < 3; ci++)
#pragma unroll
        for (int ky = 0; ky < 3; ky++)
#pragma unroll
            for (int kx = 0; kx < 3; kx++) {
                int hh = h + ky - 1, ww = w + kx - 1;
                bool ok = ((unsigned)hh < 256u) && ((unsigned)ww < 256u);
                in[(ci * 3 + ky) * 3 + kx] = ok ? xb[(ci << 16) + (hh << 8) + ww] : 0.f;
            }
    __hip_bfloat16* ob = out + (size_t)b * 16 * 65536 + (h << 8) + w;
#pragma unroll 4
    for (int co = 0; co < 16; co++) {
        float acc = bias[co];          // uniform index -> s_load
#pragma unroll
        for (int k = 0; k < 27; k++) acc += in[k] * wgt[co * 27 + k];
        ob[(size_t)co << 16] = __float2bfloat16(silu_f(acc));
    }
}

// ------- s-branch conv1: MFMA GEMM, fp8 out, co-split, FROZEN -------
#define C1K 40   // padded k-stride (shorts)
__global__ __launch_bounds__(256) void conv1s_mfma(
    const float* __restrict__ x, const float* __restrict__ wgt,
    const float* __restrict__ bias, char* __restrict__ out8)
{
    __shared__ __align__(16) short Ps[128 * C1K];  // [pixel][k] 10240 B
    __shared__ __align__(16) short Ws[64 * C1K];   // [co][k]     5120 B
    int tid = threadIdx.x;
    int g = blockIdx.x;                 // 8192: b*1024 + hhalf*2 + cohalf
    int b = g >> 10, rem = g & 1023;
    int hh2 = rem >> 1;                 // 0..511
    int h = hh2 >> 1, w0 = (hh2 & 1) * 128;
    int coB = (rem & 1) * 64;           // block's global co base

    union { short s[32]; float4 v4[4]; } row;
#pragma unroll
    for (int k = 0; k < 32; k++) row.s[k] = 0;
    if (tid < 128) {
        int wpix = w0 + tid;
        const float* xb = x + (size_t)b * 3 * 65536;
#pragma unroll
        for (int ci = 0; ci < 3; ci++)
#pragma unroll
            for (int ky = 0; ky < 3; ky++)
#pragma unroll
                for (int kx = 0; kx < 3; kx++) {
                    int hhp = h + ky - 1, ww = wpix + kx - 1;
                    float v = 0.f;
                    if (((unsigned)hhp < 256u) && ((unsigned)ww < 256u))
                        v = xb[(ci << 16) + (hhp << 8) + ww];
                    row.s[ci * 9 + ky * 3 + kx] = f2bf(v);
                }
#pragma unroll
        for (int j = 0; j < 4; j++) *(float4*)&Ps[tid * C1K + j * 8] = row.v4[j];
    } else if (tid < 192) {
        int co = tid - 128;             // 0..63 local
#pragma unroll
        for (int k = 0; k < 27; k++) row.s[k] = f2bf(wgt[(coB + co) * 27 + k]);
#pragma unroll
        for (int j = 0; j < 4; j++) *(float4*)&Ws[co * C1K + j * 8] = row.v4[j];
    }
    __syncthreads();

    int lane = tid & 63, wave = tid >> 6;
    int coL = (wave & 1) * 32, pxH = (wave >> 1) * 64;   // wave = 32co x 64px
    int r16 = lane & 15, q = lane >> 4, koff = q * 8;
    bf16x8 af[2], bfr[4];
#pragma unroll
    for (int mt = 0; mt < 2; mt++)
        af[mt] = *(bf16x8*)&Ws[(coL + mt * 16 + r16) * C1K + koff];
#pragma unroll
    for (int nt = 0; nt < 4; nt++)
        bfr[nt] = *(bf16x8*)&Ps[(pxH + nt * 16 + r16) * C1K + koff];
    f32x4 acc[2][4];
#pragma unroll
    for (int mt = 0; mt < 2; mt++)
#pragma unroll
        for (int nt = 0; nt < 4; nt++) {
#pragma unroll
            for (int r = 0; r < 4; r++) acc[mt][nt][r] = 0.f;
            acc[mt][nt] = __builtin_amdgcn_mfma_f32_16x16x32_bf16(
                af[mt], bfr[nt], acc[mt][nt], 0, 0, 0);
        }

    int hwb = (h << 8) + w0 + pxH;
    int* ob4 = (int*)out8 + (size_t)b * 8 * 65536 * 4;
#pragma unroll
    for (int mt = 0; mt < 2; mt++) {
        int cb = coB + coL + mt * 16 + q * 4;
        float4 bv = *(const float4*)&bias[cb];
        int cg = (coB + coL + mt * 16) >> 4;
#pragma unroll
        for (int nt = 0; nt < 4; nt++) {
            int hw = hwb + nt * 16 + r16;
            int pk = pack_fp8x4(silu_f(acc[mt][nt][0] + bv.x),
                                silu_f(acc[mt][nt][1] + bv.y),
                                silu_f(acc[mt][nt][2] + bv.z),
                                silu_f(acc[mt][nt][3] + bv.w));
            ob4[((size_t)cg * 65536 + hw) * 4 + q] = pk;
        }
    }
}

// ---- weight prep: wt8 fp8 chunk-major [pos][c16][co][e] from W[co][ci][ky][kx] f32 ----
__global__ __launch_bounds__(256) void wprep_kern(
    const float* __restrict__ w, int* __restrict__ wt8)
{
    int d = blockIdx.x * 256 + threadIdx.x;        // dword index < 36864
    int pos = d >> 12;
    int rb = (d << 2) & 16383;
    int c16 = rb >> 11, co = (rb >> 4) & 127, e0 = rb & 15;
    float f[4];
#pragma unroll
    for (int j = 0; j < 4; j++) {
        int ci = c16 * 16 + e0 + j;
        f[j] = w[co * 1152 + ci * 9 + pos];
    }
    wt8[d] = pack_fp8x4(f[0], f[1], f[2], f[3]);
}

// ------------- conv2_s implicit GEMM v17: fp8, K=128 per barrier-pair (9/block) -------------
// Spill rule: 2A+2B float4 prefetched across the barrier; 2B streamed after with
// short live ranges. LDS 24KB chunk-major, conflict-free b64 fragment reads.
__global__ __launch_bounds__(256) void conv2s_mfma(
    const char* __restrict__ a8,    // fp8 [8b][8 cg16][65536][16]
    const char* __restrict__ wt8,   // fp8 [9][8 c16][128][16]
    const float* __restrict__ bias, __hip_bfloat16* __restrict__ out)  // [T][128] bf16
{
    __shared__ __align__(16) char As[8 * 64 * 16];    //  8 KB [c16][tok][16]
    __shared__ __align__(16) char Bs[8 * 128 * 16];   // 16 KB [c16][co][16]
    int tid = threadIdx.x;
    int g = blockIdx.x;                 // 2048: b*256 + h2*2 + half
    int b = g >> 8, h2 = (g >> 1) & 127, w2base = (g & 1) * 64;
    int lane = tid & 63, wave = tid >> 6;
    int mrow = lane & 15, q = lane >> 4;

    f32x4 acc[2][4];   // [nt][mt]
#pragma unroll
    for (int i = 0; i < 2; i++)
#pragma unroll
        for (int j = 0; j < 4; j++)
#pragma unroll
            for (int r = 0; r < 4; r++) acc[i][j][r] = 0.f;

    const float4* ab4 = (const float4*)a8 + (size_t)b * 8 * 65536;
    const float4* wb4 = (const float4*)wt8;
    int cA0 = tid >> 6, tokA = tid & 63;      // A slots: tid -> (cA0,tok), tid+256 -> (cA0+4,tok)
    int sB0 = tid, sB1 = tid + 256, sB2 = tid + 512, sB3 = tid + 768;

#pragma unroll 1
    for (int pos = 0; pos < 9; pos++) {
        int ky = pos / 3, kx = pos - 3 * ky;     // uniform
        int y = 2 * h2 - 1 + ky;
        if ((unsigned)y >= 256u) continue;       // block-uniform skip (barrier-safe)
        int x = 2 * (w2base + tokA) - 1 + kx;    // in [-1, 255]
        int pix = (y << 8) + (x & 255);
        const float4* brow = wb4 + pos * 1024;
        // prefetch exactly 2A+2B across the barrier (spill rule)
        float4 a0 = make_float4(0.f, 0.f, 0.f, 0.f), a1 = a0;
        if (x >= 0) {
            a0 = ab4[(size_t)cA0 * 65536 + pix];
            a1 = ab4[(size_t)(cA0 + 4) * 65536 + pix];
        }
        float4 b0 = brow[sB0], b1 = brow[sB1];
        __syncthreads();                         // prev pos's LDS reads done
        *(float4*)&As[tid * 16]         = a0;
        *(float4*)&As[(tid + 256) * 16] = a1;
        *(float4*)&Bs[sB0 * 16] = b0;
        *(float4*)&Bs[sB1 * 16] = b1;
        // remaining B half: short live ranges
        float4 b2 = brow[sB2], b3 = brow[sB3];
        *(float4*)&Bs[sB2 * 16] = b2;
        *(float4*)&Bs[sB3 * 16] = b3;
        __syncthreads();                         // tiles ready
#pragma unroll
        for (int kc = 0; kc < 4; kc++) {         // four K=32 MFMA steps
            int cl = kc * 2 + (q >> 1), off = (q & 1) * 8;
            long afr[4], bfr[2];
#pragma unroll
            for (int mt = 0; mt < 4; mt++)
                afr[mt] = *(long*)&As[(cl * 64 + mt * 16 + mrow) * 16 + off];
#pragma unroll
            for (int nt = 0; nt < 2; nt++)
                bfr[nt] = *(long*)&Bs[(cl * 128 + wave * 32 + nt * 16 + mrow) * 16 + off];
#pragma unroll
            for (int nt = 0; nt < 2; nt++)
#pragma unroll
                for (int mt = 0; mt < 4; mt++)
                    acc[nt][mt] = __builtin_amdgcn_mfma_f32_16x16x32_fp8_fp8(
                        afr[mt], bfr[nt], acc[nt][mt], 0, 0, 0);
        }
    }
    int rowg = q * 4;
    size_t tbase = (size_t)g * 64;
#pragma unroll
    for (int nt = 0; nt < 2; nt++) {
        int co = wave * 32 + nt * 16 + mrow;
        float bvs = bias[co];
#pragma unroll
        for (int mt = 0; mt < 4; mt++)
#pragma unroll
            for (int r = 0; r < 4; r++) {
                int m = mt * 16 + rowg + r;
                out[(tbase + m) * 128 + co] =
                    __float2bfloat16(silu_f(acc[nt][mt][r] + bvs));
            }
    }
}

// ------- n-branch conv2 (bf16 in) FUSED with memcell softmax: writes wmat [T,32] -------
__global__ __launch_bounds__(256) void conv2n_fused(
    const __hip_bfloat16* __restrict__ in, const float* __restrict__ wgt,
    const float* __restrict__ bias, const float* __restrict__ ck,
    float* __restrict__ wout)
{
    int idx = blockIdx.x * 256 + threadIdx.x;      // token (b,h2,w2)
    int w2 = idx & 127, h2 = (idx >> 7) & 127, b = idx >> 14;
    const __hip_bfloat16* ib = in + (size_t)b * 16 * 65536;
    float acc[16];
#pragma unroll
    for (int co = 0; co < 16; co++) acc[co] = bias[co];
    int h0 = 2 * h2 - 1, w0 = 2 * w2 - 1;
    for (int ci = 0; ci < 16; ci++) {
        float t[9];
#pragma unroll
        for (int ky = 0; ky < 3; ky++)
#pragma unroll
            for (int kx = 0; kx < 3; kx++) {
                int hh = h0 + ky, ww = w0 + kx;
                bool ok = ((unsigned)hh < 256u) && ((unsigned)ww < 256u);
                t[ky * 3 + kx] = ok ? __bfloat162float(ib[((size_t)ci << 16) + (hh << 8) + ww]) : 0.f;
            }
#pragma unroll
        for (int co = 0; co < 16; co++)
#pragma unroll
            for (int k = 0; k < 9; k++)
                acc[co] += t[k] * wgt[(co * 16 + ci) * 9 + k];
    }
    float zv[16];
#pragma unroll
    for (int co = 0; co < 16; co++) zv[co] = silu_f(acc[co]);
    float lg[32]; float mx = -1e30f;
#pragma unroll
    for (int m = 0; m < 32; m++) {
        float a = 0.f;
#pragma unroll
        for (int n = 0; n < 16; n++) a += zv[n] * ck[m * 16 + n];   // uniform -> s_load
        a *= 0.25f;
        lg[m] = a; mx = fmaxf(mx, a);
    }
    float s = 0.f;
#pragma unroll
    for (int m = 0; m < 32; m++) { lg[m] = __expf(lg[m] - mx); s += lg[m]; }
    float inv = 1.f / s;      // precise: softmax feeds everything downstream
    float4* wp = (float4*)(wout + (size_t)idx * 32);
#pragma unroll
    for (int m = 0; m < 8; m++)
        wp[m] = make_float4(lg[4 * m] * inv, lg[4 * m + 1] * inv,
                            lg[4 * m + 2] * inv, lg[4 * m + 3] * inv);
}

// ---------------- WtW/WtT partials: 1024 blocks x 128 tokens, no atomics ----------------
__global__ __launch_bounds__(256) void memcell_acc_kern(
    const float* __restrict__ wmat, const __hip_bfloat16* __restrict__ tstar,
    float* __restrict__ part)
{
    __shared__ float ws[64][32];     // 8 KB
    __shared__ float ts[64 * 128];   // 32 KB
    int tid = threadIdx.x;
    int sg = tid & 31, mg = tid >> 5;
    int mW = tid & 31, m2 = (tid >> 5) * 4;
    float accT[16], accW[4];
#pragma unroll
    for (int i = 0; i < 16; i++) accT[i] = 0.f;
#pragma unroll
    for (int i = 0; i < 4; i++) accW[i] = 0.f;

#pragma unroll 1
    for (int cc = 0; cc < 2; cc++) {
        int c = blockIdx.x * 2 + cc;
        size_t base = (size_t)c * 64;
        __syncthreads();
        {
            const float4* src = (const float4*)(wmat + base * 32);
            float4* dst = (float4*)&ws[0][0];
#pragma unroll
            for (int i = 0; i < 2; i++) dst[tid + 256 * i] = src[tid + 256 * i];
            const float4* src2 = (const float4*)(tstar + base * 128);
#pragma unroll
            for (int i = 0; i < 4; i++) {
                union { float4 v; unsigned short us[8]; } u;
                u.v = src2[tid + 256 * i];
                float* d = &ts[(tid + 256 * i) * 8];
                float4 lo = make_float4(bf2f(u.us[0]), bf2f(u.us[1]), bf2f(u.us[2]), bf2f(u.us[3]));
                float4 hi = make_float4(bf2f(u.us[4]), bf2f(u.us[5]), bf2f(u.us[6]), bf2f(u.us[7]));
                *(float4*)d = lo; *(float4*)(d + 4) = hi;
            }
        }
        __syncthreads();
        for (int t = 0; t < 64; t++) {
            float4 wv = *(const float4*)&ws[t][mg * 4];
            float4 sv = *(const float4*)&ts[t * 128 + sg * 4];
            accT[0]  += wv.x * sv.x; accT[1]  += wv.x * sv.y; accT[2]  += wv.x * sv.z; accT[3]  += wv.x * sv.w;
            accT[4]  += wv.y * sv.x; accT[5]  += wv.y * sv.y; accT[6]  += wv.y * sv.z; accT[7]  += wv.y * sv.w;
            accT[8]  += wv.z * sv.x; accT[9]  += wv.z * sv.y; accT[10] += wv.z * sv.z; accT[11] += wv.z * sv.w;
            accT[12] += wv.w * sv.x; accT[13] += wv.w * sv.y; accT[14] += wv.w * sv.z; accT[15] += wv.w * sv.w;
            float wa = ws[t][mW];
            float4 wb = *(const float4*)&ws[t][m2];
            accW[0] += wa * wb.x; accW[1] += wa * wb.y;
            accW[2] += wa * wb.z; accW[3] += wa * wb.w;
        }
    }
    float* pb = part + (size_t)blockIdx.x * 5120;
#pragma unroll
    for (int i = 0; i < 16; i++) pb[i * 256 + tid] = accT[i];
#pragma unroll
    for (int i = 0; i < 4; i++) pb[4096 + i * 256 + tid] = accW[i];
}

// ---------------- reduce 1024 partials -> WtT [32,128], WtW [32,32] ----------------
__global__ __launch_bounds__(256) void memcell_reduce_kern(
    const float* __restrict__ part, float* __restrict__ WtT, float* __restrict__ WtW)
{
    int gid = blockIdx.x * 256 + threadIdx.x;   // 81920
    int j = gid % 5120, seg = gid / 5120;
    const float* p = part + (size_t)seg * 64 * 5120 + j;
    float s = 0.f;
#pragma unroll 8
    for (int k = 0; k < 64; k++) s += p[(size_t)k * 5120];
    int i = j >> 8, t = j & 255;
    if (j < 4096) {
        int sg = t & 31, mg = t >> 5;
        atomicAdd(&WtT[(mg * 4 + (i >> 2)) * 128 + sg * 4 + (i & 3)], s);
    } else {
        int i2 = i - 16;
        int mW = t & 31, m2 = (t >> 5) * 4;
        atomicAdd(&WtW[mW * 32 + m2 + i2], s);
    }
}

// ------- cell_v_new = cell_v + ALPHA*(WtT - WtW @ cell_v)  [32,128] -------
__global__ __launch_bounds__(256) void cvnew_kern(
    const float* __restrict__ cv, const float* __restrict__ WtW,
    const float* __restrict__ WtT, float* __restrict__ cvn)
{
    int idx = blockIdx.x * 256 + threadIdx.x;   // 4096
    int s = idx & 127, m = idx >> 7;
    float g = WtT[idx];
#pragma unroll
    for (int j = 0; j < 32; j++) g -= WtW[m * 32 + j] * cv[j * 128 + s];
    cvn[idx] = cv[idx] + ALPHA_F * g;
}

// ------- E[m][pos*4+co] = sum_ci cvn[m][ci] * dw[ci][co][kh][kw] -------
__global__ __launch_bounds__(256) void emat_kern(
    const float* __restrict__ cvn, const float* __restrict__ dw, float* __restrict__ E)
{
    int idx = blockIdx.x * 256 + threadIdx.x;   // 2048
    int m = idx >> 6, j = idx & 63;
    int pos = j >> 2, co = j & 3;
    float s = 0.f;
    if (co < 3) {
        const float* cv = cvn + m * 128;        // uniform per 64-lane group -> s_loads
        for (int ci = 0; ci < 128; ci++)
            s += cv[ci] * dw[ci * 48 + co * 16 + pos];
    }
    E[idx] = s;
}

// ------- t64[pos][Tglobal][4] = (wmat[T,32] @ E[32,64]) pos-major -------
__global__ __launch_bounds__(256) void tread64_kern(
    const float* __restrict__ wmat, const float* __restrict__ E, float* __restrict__ t64)
{
    int t = blockIdx.x * 256 + threadIdx.x;
    float wv[32];
    const float4* wp = (const float4*)(wmat + (size_t)t * 32);
#pragma unroll
    for (int i = 0; i < 8; i++) {
        float4 v = wp[i];
        wv[4 * i] = v.x; wv[4 * i + 1] = v.y; wv[4 * i + 2] = v.z; wv[4 * i + 3] = v.w;
    }
    f32x4 acc[16];
#pragma unroll
    for (int i = 0; i < 16; i++)
#pragma unroll
        for (int r = 0; r < 4; r++) acc[i][r] = 0.f;
    const f32x4* E4 = (const f32x4*)E;
#pragma unroll 4
    for (int m = 0; m < 32; m++) {
        float wm = wv[m];
#pragma unroll
        for (int i = 0; i < 16; i++) {
            f32x4 e = E4[m * 16 + i];           // uniform -> s_load_dwordx4
#pragma unroll
            for (int r = 0; r < 4; r++) acc[i][r] += wm * e[r];
        }
    }
    f32x4* ob = (f32x4*)t64;
#pragma unroll
    for (int i = 0; i < 16; i++)
        ob[(size_t)i * TTOT + t] = acc[i];      // lane-consecutive 16B per pos-plane
}

// ------- decoder gather: dec1 = silu(sum of 4 taps from t64 + bias) -------
__global__ __launch_bounds__(256) void dec_gather_kern(
    const float* __restrict__ t64, const float* __restrict__ db, float* __restrict__ out)
{
    int g = blockIdx.x;                   // 512: b*64 + hb*8 + wb
    int wb = g & 7, hb = (g >> 3) & 7, b = g >> 6;
    int tx = threadIdx.x & 15, ty = threadIdx.x >> 4;
    int h2 = hb * 16 + ty, w2 = wb * 16 + tx;

    float mh[3], mw[3];
    int ihc[3], iwc[3];
#pragma unroll
    for (int a = 0; a < 3; a++) {
        int v = h2 - 1 + a;
        mh[a] = ((unsigned)v < 128u) ? 1.f : 0.f;
        ihc[a] = v < 0 ? 0 : (v > 127 ? 127 : v);
        v = w2 - 1 + a;
        mw[a] = ((unsigned)v < 128u) ? 1.f : 0.f;
        iwc[a] = v < 0 ? 0 : (v > 127 ? 127 : v);
    }
    float acc[2][2][3];
#pragma unroll
    for (int ph = 0; ph < 2; ph++)
#pragma unroll
        for (int pw = 0; pw < 2; pw++)
#pragma unroll
            for (int co = 0; co < 3; co++) acc[ph][pw][co] = db[co];

    const int RA[4] = {0, 1, 1, 2}, RP[4] = {0, 0, 1, 1}, RK[4] = {3, 1, 2, 0};
    size_t tokb = (size_t)b * 16384;
#pragma unroll
    for (int ri = 0; ri < 4; ri++)
#pragma unroll
        for (int cj = 0; cj < 4; cj++) {
            int a = RA[ri], c = RA[cj];
            float m = mh[a] * mw[c];
            size_t tok = tokb + (ihc[a] << 7) + iwc[c];
            int pos = RK[ri] * 4 + RK[cj];
            float4 v = *(const float4*)&t64[((size_t)pos * TTOT + tok) * 4];
            int ph = RP[ri], pw = RP[cj];
            acc[ph][pw][0] += m * v.x;
            acc[ph][pw][1] += m * v.y;
            acc[ph][pw][2] += m * v.z;
        }
    int h = 2 * h2, w = 2 * w2;
#pragma unroll
    for (int ph = 0; ph < 2; ph++)
#pragma unroll
        for (int co = 0; co < 3; co++) {
            float2 v = make_float2(silu_f(acc[ph][0][co]), silu_f(acc[ph][1][co]));
            *(float2*)&out[(size_t)b * 3 * 65536 + (size_t)co * 65536 + ((size_t)(h + ph) << 8) + w] = v;
        }
}

extern "C" void kernel_launch(void* const* d_in, const int* in_sizes, int n_in,
                              void* d_out, int out_size, void* d_ws, size_t ws_size,
                              hipStream_t stream)
{
    const float* x      = (const float*)d_in[0];
    const float* e0n_w1 = (const float*)d_in[1];
    const float* e0n_b1 = (const float*)d_in[2];
    const float* e0n_w2 = (const float*)d_in[3];
    const float* e0n_b2 = (const float*)d_in[4];
    const float* e0s_w1 = (const float*)d_in[5];
    const float* e0s_b1 = (const float*)d_in[6];
    const float* e0s_w2 = (const float*)d_in[7];
    const float* e0s_b2 = (const float*)d_in[8];
    const float* d0_dw  = (const float*)d_in[9];
    const float* d0_db  = (const float*)d_in[10];
    const float* d0_cw  = (const float*)d_in[11];
    const float* d0_cb  = (const float*)d_in[12];
    const float* cell_k = (const float*)d_in[13];
    const float* cell_v = (const float*)d_in[14];
    float* outp = (float*)d_out;

    char* ws = (char*)d_ws;
    char* a_s8             = ws;                              // 67 MB fp8
    __hip_bfloat16* t_star = (__hip_bfloat16*)(ws + 134217728);
    __hip_bfloat16* a_n    = (__hip_bfloat16*)(ws + 167772160); // 33.5 MB bf16 (own slot)
    char* wt8     = (char*)(ws + 201326592);
    float* part   = (float*)(ws + 201850880);                 // 21 MB partials
    float* Emat   = (float*)(ws + 224000000);                 // 8 KB
    float* wmat   = (float*)(ws + 243269632);
    float* WtW    = (float*)(ws + 260046848);
    float* WtT    = (float*)(ws + 260050944);
    float* cvn    = (float*)(ws + 260067328);
    float* t64    = (float*)(ws);               // reuse a_s8 region (dead after conv2s)
    float* dec1   = (float*)(ws + 67108864);

    // n-branch encoder (bf16 a_n); conv2n writes wmat directly (softmax fused)
    conv1n_kern<<<2048, 256, 0, stream>>>(x, e0n_w1, e0n_b1, a_n);
    conv2n_fused<<<512, 256, 0, stream>>>(a_n, e0n_w2, e0n_b2, cell_k, wmat);
    // s-branch encoder: fp8 MFMA conv1 (co-split) -> fp8 MFMA implicit-GEMM conv2
    wprep_kern<<<144, 256, 0, stream>>>(e0s_w2, (int*)wt8);
    conv1s_mfma<<<8192, 256, 0, stream>>>(x, e0s_w1, e0s_b1, a_s8);
    conv2s_mfma<<<2048, 256, 0, stream>>>(a_s8, wt8, e0s_b2, t_star);
    // memcell
    hipMemsetAsync(WtW, 0, (1024 + 4096) * sizeof(float), stream);
    memcell_acc_kern<<<1024, 256, 0, stream>>>(wmat, t_star, part);
    memcell_reduce_kern<<<320, 256, 0, stream>>>(part, WtT, WtW);
    cvnew_kern<<<16, 256, 0, stream>>>(cell_v, WtW, WtT, cvn);
    // decoder: fold deconv weights through cvn, then gather (pos-major t64)
    emat_kern<<<8, 256, 0, stream>>>(cvn, d0_dw, Emat);
    tread64_kern<<<512, 256, 0, stream>>>(wmat, Emat, t64);
    dec_gather_kern<<<512, 256, 0, stream>>>(t64, d0_db, dec1);
    conv1_silu<3><<<2048, 256, 0, stream>>>(dec1, d0_cw, d0_cb, outp);
}

// Round 21
// 296.692 us; speedup vs baseline: 1.0129x; 1.0129x over previous
//
#include <hip/hip_runtime.h>
#include <hip/hip_bf16.h>

// CPSFMemcellAutoencoder: B=8, 256x256 input, N=16, S=128, M=32, T=131072.
// REVERTED to R19 best-known config (296.8us). R20's two-change round (a_n bf16 +
// conv2s K=128 restage) regressed +3.7us with muddy attribution; both reverted.
// Workspace layout (~260 MB):
//   [0, 67108864)             a_s8  : fp8 [8b][8 cg16][65536 hw][16 ci]
//     REUSED: t64 at [0, 33554432)  : POS-MAJOR [16 pos][131072 tok][4] f32
//   dec1 at [67108864, 73400320)    : [8,3,256,256] f32
//   [134217728, 167772160)    t_star: [T,128] bf16 token-major
//   [201326592, 234881024)    a_n   : [8,16,256,256] f32 (n-branch)
//     REUSED: wt8  at +201326592 (147456 B conv2_s weights fp8 chunk-major)
//     REUSED: part at +201850880 (1024 x 5120 f32 partials)
//     REUSED: Emat at +224000000 (32*64 f32)
//   [243269632, 260046848)    wmat  : [T,32] f32  (written by conv2n_fused)
//   [260046848, 260050944)    WtW / [260050944, 260067328) WtT / [260067328, ...) cvn

#define ALPHA_F 1e-6f
#define TTOT 131072

typedef __attribute__((ext_vector_type(8))) short bf16x8;
typedef __attribute__((ext_vector_type(4))) float f32x4;

__device__ __forceinline__ float silu_f(float x) {
    return x * __builtin_amdgcn_rcpf(1.f + __expf(-x));
}

__device__ __forceinline__ short f2bf(float f) {
    __hip_bfloat16 h = __float2bfloat16(f);
    union { __hip_bfloat16 b; short s; } u; u.b = h; return u.s;
}

__device__ __forceinline__ float bf2f(unsigned short s) {
    union { unsigned u; float f; } c; c.u = (unsigned)s << 16; return c.f;
}

__device__ __forceinline__ int pack_fp8x4(float a, float b, float c, float d) {
    int lo = __builtin_amdgcn_cvt_pk_fp8_f32(a, b, 0, false);
    return  __builtin_amdgcn_cvt_pk_fp8_f32(c, d, lo, true);
}

// ---------------- conv 3x3, Cin=3, stride 1, pad 1, + bias + silu (NCHW f32 out) ----------------
template<int CO>
__global__ __launch_bounds__(256) void conv1_silu(
    const float* __restrict__ x, const float* __restrict__ wgt,
    const float* __restrict__ bias, float* __restrict__ out)
{
    int idx = blockIdx.x * 256 + threadIdx.x;      // (b,h,w)
    int w = idx & 255, h = (idx >> 8) & 255, b = idx >> 16;
    const float* xb = x + (size_t)b * 3 * 65536;
    float in[27];
#pragma unroll
    for (int ci = 0; ci < 3; ci++)
#pragma unroll
        for (int ky = 0; ky < 3; ky++)
#pragma unroll
            for (int kx = 0; kx < 3; kx++) {
                int hh = h + ky - 1, ww = w + kx - 1;
                bool ok = ((unsigned)hh < 256u) && ((unsigned)ww < 256u);
                in[(ci * 3 + ky) * 3 + kx] = ok ? xb[(ci << 16) + (hh << 8) + ww] : 0.f;
            }
    float* ob = out + (size_t)b * CO * 65536 + (h << 8) + w;
#pragma unroll 4
    for (int co = 0; co < CO; co++) {
        float acc = bias[co];          // uniform index -> s_load
#pragma unroll
        for (int k = 0; k < 27; k++) acc += in[k] * wgt[co * 27 + k];
        ob[(size_t)co << 16] = silu_f(acc);
    }
}

// ------- s-branch conv1: MFMA GEMM, fp8 out, co-split (128px x 64co per block), FROZEN -------
#define C1K 40   // padded k-stride (shorts)
__global__ __launch_bounds__(256) void conv1s_mfma(
    const float* __restrict__ x, const float* __restrict__ wgt,
    const float* __restrict__ bias, char* __restrict__ out8)
{
    __shared__ __align__(16) short Ps[128 * C1K];  // [pixel][k] 10240 B
    __shared__ __align__(16) short Ws[64 * C1K];   // [co][k]     5120 B
    int tid = threadIdx.x;
    int g = blockIdx.x;                 // 8192: b*1024 + hhalf*2 + cohalf
    int b = g >> 10, rem = g & 1023;
    int hh2 = rem >> 1;                 // 0..511
    int h = hh2 >> 1, w0 = (hh2 & 1) * 128;
    int coB = (rem & 1) * 64;           // block's global co base

    union { short s[32]; float4 v4[4]; } row;
#pragma unroll
    for (int k = 0; k < 32; k++) row.s[k] = 0;
    if (tid < 128) {
        int wpix = w0 + tid;
        const float* xb = x + (size_t)b * 3 * 65536;
#pragma unroll
        for (int ci = 0; ci < 3; ci++)
#pragma unroll
            for (int ky = 0; ky < 3; ky++)
#pragma unroll
                for (int kx = 0; kx < 3; kx++) {
                    int hhp = h + ky - 1, ww = wpix + kx - 1;
                    float v = 0.f;
                    if (((unsigned)hhp < 256u) && ((unsigned)ww < 256u))
                        v = xb[(ci << 16) + (hhp << 8) + ww];
                    row.s[ci * 9 + ky * 3 + kx] = f2bf(v);
                }
#pragma unroll
        for (int j = 0; j < 4; j++) *(float4*)&Ps[tid * C1K + j * 8] = row.v4[j];
    } else if (tid < 192) {
        int co = tid - 128;             // 0..63 local
#pragma unroll
        for (int k = 0; k < 27; k++) row.s[k] = f2bf(wgt[(coB + co) * 27 + k]);
#pragma unroll
        for (int j = 0; j < 4; j++) *(float4*)&Ws[co * C1K + j * 8] = row.v4[j];
    }
    __syncthreads();

    int lane = tid & 63, wave = tid >> 6;
    int coL = (wave & 1) * 32, pxH = (wave >> 1) * 64;   // wave = 32co x 64px
    int r16 = lane & 15, q = lane >> 4, koff = q * 8;
    bf16x8 af[2], bfr[4];
#pragma unroll
    for (int mt = 0; mt < 2; mt++)
        af[mt] = *(bf16x8*)&Ws[(coL + mt * 16 + r16) * C1K + koff];
#pragma unroll
    for (int nt = 0; nt < 4; nt++)
        bfr[nt] = *(bf16x8*)&Ps[(pxH + nt * 16 + r16) * C1K + koff];
    f32x4 acc[2][4];
#pragma unroll
    for (int mt = 0; mt < 2; mt++)
#pragma unroll
        for (int nt = 0; nt < 4; nt++) {
#pragma unroll
            for (int r = 0; r < 4; r++) acc[mt][nt][r] = 0.f;
            acc[mt][nt] = __builtin_amdgcn_mfma_f32_16x16x32_bf16(
                af[mt], bfr[nt], acc[mt][nt], 0, 0, 0);
        }

    int hwb = (h << 8) + w0 + pxH;
    int* ob4 = (int*)out8 + (size_t)b * 8 * 65536 * 4;
#pragma unroll
    for (int mt = 0; mt < 2; mt++) {
        int cb = coB + coL + mt * 16 + q * 4;
        float4 bv = *(const float4*)&bias[cb];
        int cg = (coB + coL + mt * 16) >> 4;
#pragma unroll
        for (int nt = 0; nt < 4; nt++) {
            int hw = hwb + nt * 16 + r16;
            int pk = pack_fp8x4(silu_f(acc[mt][nt][0] + bv.x),
                                silu_f(acc[mt][nt][1] + bv.y),
                                silu_f(acc[mt][nt][2] + bv.z),
                                silu_f(acc[mt][nt][3] + bv.w));
            ob4[((size_t)cg * 65536 + hw) * 4 + q] = pk;
        }
    }
}

// ---- weight prep: wt8 fp8 chunk-major [pos][c16=ci/16][co][e=ci%16] from W[co][ci][ky][kx] f32 ----
__global__ __launch_bounds__(256) void wprep_kern(
    const float* __restrict__ w, int* __restrict__ wt8)
{
    int d = blockIdx.x * 256 + threadIdx.x;        // dword index < 36864
    int pos = d >> 12;
    int rb = (d << 2) & 16383;
    int c16 = rb >> 11, co = (rb >> 4) & 127, e0 = rb & 15;
    float f[4];
#pragma unroll
    for (int j = 0; j < 4; j++) {
        int ci = c16 * 16 + e0 + j;
        f[j] = w[co * 1152 + ci * 9 + pos];
    }
    wt8[d] = pack_fp8x4(f[0], f[1], f[2], f[3]);
}

// ------------- conv2_s implicit GEMM (R16-proven): fp8 operands, K=64 stages -------------
__global__ __launch_bounds__(256) void conv2s_mfma(
    const char* __restrict__ a8,    // fp8 [8b][8 cg16][65536][16]
    const char* __restrict__ wt8,   // fp8 [9][8 c16][128][16]
    const float* __restrict__ bias, __hip_bfloat16* __restrict__ out)  // [T][128] bf16
{
    __shared__ __align__(16) char As[4 * 64 * 16];    // 4 KB
    __shared__ __align__(16) char Bs[4 * 128 * 16];   // 8 KB
    int tid = threadIdx.x;
    int g = blockIdx.x;                 // 2048: b*256 + h2*2 + half
    int b = g >> 8, h2 = (g >> 1) & 127, w2base = (g & 1) * 64;
    int lane = tid & 63, wave = tid >> 6;
    int mrow = lane & 15, q = lane >> 4;

    f32x4 acc[2][4];   // [nt][mt]
#pragma unroll
    for (int i = 0; i < 2; i++)
#pragma unroll
        for (int j = 0; j < 4; j++)
#pragma unroll
            for (int r = 0; r < 4; r++) acc[i][j][r] = 0.f;

    const float4* ab4 = (const float4*)a8 + (size_t)b * 8 * 65536;
    const float4* wb4 = (const float4*)wt8;
    int cA = tid >> 6, tokA = tid & 63;
    int sB0 = tid, sB1 = tid + 256;

#pragma unroll 1
    for (int pos = 0; pos < 9; pos++) {
        int ky = pos / 3, kx = pos - 3 * ky;     // uniform
        int y = 2 * h2 - 1 + ky;
        if ((unsigned)y >= 256u) continue;       // block-uniform skip (barrier-safe)
        int x = 2 * (w2base + tokA) - 1 + kx;    // in [-1, 255]
        int pix = (y << 8) + (x & 255);
#pragma unroll 1
        for (int cc = 0; cc < 2; cc++) {         // K=64 stages (4 c16 chunks each)
            float4 a0 = make_float4(0.f, 0.f, 0.f, 0.f);
            if (x >= 0) a0 = ab4[(size_t)(cc * 4 + cA) * 65536 + pix];
            const float4* brow = wb4 + pos * 1024 + cc * 512;
            float4 b0 = brow[sB0], b1 = brow[sB1];
            __syncthreads();
            *(float4*)&As[tid * 16] = a0;
            *(float4*)&Bs[sB0 * 16] = b0;
            *(float4*)&Bs[sB1 * 16] = b1;
            __syncthreads();
#pragma unroll
            for (int kc = 0; kc < 2; kc++) {
                int cl = kc * 2 + (q >> 1), off = (q & 1) * 8;
                long afr[4], bfr[2];
#pragma unroll
                for (int mt = 0; mt < 4; mt++)
                    afr[mt] = *(long*)&As[(cl * 64 + mt * 16 + mrow) * 16 + off];
#pragma unroll
                for (int nt = 0; nt < 2; nt++)
                    bfr[nt] = *(long*)&Bs[(cl * 128 + wave * 32 + nt * 16 + mrow) * 16 + off];
#pragma unroll
                for (int nt = 0; nt < 2; nt++)
#pragma unroll
                    for (int mt = 0; mt < 4; mt++)
                        acc[nt][mt] = __builtin_amdgcn_mfma_f32_16x16x32_fp8_fp8(
                            afr[mt], bfr[nt], acc[nt][mt], 0, 0, 0);
            }
        }
    }
    int rowg = q * 4;
    size_t tbase = (size_t)g * 64;
#pragma unroll
    for (int nt = 0; nt < 2; nt++) {
        int co = wave * 32 + nt * 16 + mrow;
        float bvs = bias[co];
#pragma unroll
        for (int mt = 0; mt < 4; mt++)
#pragma unroll
            for (int r = 0; r < 4; r++) {
                int m = mt * 16 + rowg + r;
                out[(tbase + m) * 128 + co] =
                    __float2bfloat16(silu_f(acc[nt][mt][r] + bvs));
            }
    }
}

// ------- n-branch conv2 (16->16, s2) FUSED with memcell softmax: writes wmat [T,32] -------
__global__ __launch_bounds__(256) void conv2n_fused(
    const float* __restrict__ in, const float* __restrict__ wgt,
    const float* __restrict__ bias, const float* __restrict__ ck,
    float* __restrict__ wout)
{
    int idx = blockIdx.x * 256 + threadIdx.x;      // token (b,h2,w2)
    int w2 = idx & 127, h2 = (idx >> 7) & 127, b = idx >> 14;
    const float* ib = in + (size_t)b * 16 * 65536;
    float acc[16];
#pragma unroll
    for (int co = 0; co < 16; co++) acc[co] = bias[co];
    int h0 = 2 * h2 - 1, w0 = 2 * w2 - 1;
    for (int ci = 0; ci < 16; ci++) {
        float t[9];
#pragma unroll
        for (int ky = 0; ky < 3; ky++)
#pragma unroll
            for (int kx = 0; kx < 3; kx++) {
                int hh = h0 + ky, ww = w0 + kx;
                bool ok = ((unsigned)hh < 256u) && ((unsigned)ww < 256u);
                t[ky * 3 + kx] = ok ? ib[((size_t)ci << 16) + (hh << 8) + ww] : 0.f;
            }
#pragma unroll
        for (int co = 0; co < 16; co++)
#pragma unroll
            for (int k = 0; k < 9; k++)
                acc[co] += t[k] * wgt[(co * 16 + ci) * 9 + k];
    }
    float zv[16];
#pragma unroll
    for (int co = 0; co < 16; co++) zv[co] = silu_f(acc[co]);
    float lg[32]; float mx = -1e30f;
#pragma unroll
    for (int m = 0; m < 32; m++) {
        float a = 0.f;
#pragma unroll
        for (int n = 0; n < 16; n++) a += zv[n] * ck[m * 16 + n];   // uniform -> s_load
        a *= 0.25f;
        lg[m] = a; mx = fmaxf(mx, a);
    }
    float s = 0.f;
#pragma unroll
    for (int m = 0; m < 32; m++) { lg[m] = __expf(lg[m] - mx); s += lg[m]; }
    float inv = 1.f / s;      // precise: softmax feeds everything downstream
    float4* wp = (float4*)(wout + (size_t)idx * 32);
#pragma unroll
    for (int m = 0; m < 8; m++)
        wp[m] = make_float4(lg[4 * m] * inv, lg[4 * m + 1] * inv,
                            lg[4 * m + 2] * inv, lg[4 * m + 3] * inv);
}

// ---------------- WtW/WtT partials: 1024 blocks x 128 tokens, no atomics ----------------
__global__ __launch_bounds__(256) void memcell_acc_kern(
    const float* __restrict__ wmat, const __hip_bfloat16* __restrict__ tstar,
    float* __restrict__ part)
{
    __shared__ float ws[64][32];     // 8 KB
    __shared__ float ts[64 * 128];   // 32 KB
    int tid = threadIdx.x;
    int sg = tid & 31, mg = tid >> 5;
    int mW = tid & 31, m2 = (tid >> 5) * 4;
    float accT[16], accW[4];
#pragma unroll
    for (int i = 0; i < 16; i++) accT[i] = 0.f;
#pragma unroll
    for (int i = 0; i < 4; i++) accW[i] = 0.f;

#pragma unroll 1
    for (int cc = 0; cc < 2; cc++) {
        int c = blockIdx.x * 2 + cc;
        size_t base = (size_t)c * 64;
        __syncthreads();
        {
            const float4* src = (const float4*)(wmat + base * 32);
            float4* dst = (float4*)&ws[0][0];
#pragma unroll
            for (int i = 0; i < 2; i++) dst[tid + 256 * i] = src[tid + 256 * i];
            const float4* src2 = (const float4*)(tstar + base * 128);
#pragma unroll
            for (int i = 0; i < 4; i++) {
                union { float4 v; unsigned short us[8]; } u;
                u.v = src2[tid + 256 * i];
                float* d = &ts[(tid + 256 * i) * 8];
                float4 lo = make_float4(bf2f(u.us[0]), bf2f(u.us[1]), bf2f(u.us[2]), bf2f(u.us[3]));
                float4 hi = make_float4(bf2f(u.us[4]), bf2f(u.us[5]), bf2f(u.us[6]), bf2f(u.us[7]));
                *(float4*)d = lo; *(float4*)(d + 4) = hi;
            }
        }
        __syncthreads();
        for (int t = 0; t < 64; t++) {
            float4 wv = *(const float4*)&ws[t][mg * 4];
            float4 sv = *(const float4*)&ts[t * 128 + sg * 4];
            accT[0]  += wv.x * sv.x; accT[1]  += wv.x * sv.y; accT[2]  += wv.x * sv.z; accT[3]  += wv.x * sv.w;
            accT[4]  += wv.y * sv.x; accT[5]  += wv.y * sv.y; accT[6]  += wv.y * sv.z; accT[7]  += wv.y * sv.w;
            accT[8]  += wv.z * sv.x; accT[9]  += wv.z * sv.y; accT[10] += wv.z * sv.z; accT[11] += wv.z * sv.w;
            accT[12] += wv.w * sv.x; accT[13] += wv.w * sv.y; accT[14] += wv.w * sv.z; accT[15] += wv.w * sv.w;
            float wa = ws[t][mW];
            float4 wb = *(const float4*)&ws[t][m2];
            accW[0] += wa * wb.x; accW[1] += wa * wb.y;
            accW[2] += wa * wb.z; accW[3] += wa * wb.w;
        }
    }
    float* pb = part + (size_t)blockIdx.x * 5120;
#pragma unroll
    for (int i = 0; i < 16; i++) pb[i * 256 + tid] = accT[i];
#pragma unroll
    for (int i = 0; i < 4; i++) pb[4096 + i * 256 + tid] = accW[i];
}

// ---------------- reduce 1024 partials -> WtT [32,128], WtW [32,32] ----------------
__global__ __launch_bounds__(256) void memcell_reduce_kern(
    const float* __restrict__ part, float* __restrict__ WtT, float* __restrict__ WtW)
{
    int gid = blockIdx.x * 256 + threadIdx.x;   // 81920
    int j = gid % 5120, seg = gid / 5120;
    const float* p = part + (size_t)seg * 64 * 5120 + j;
    float s = 0.f;
#pragma unroll 8
    for (int k = 0; k < 64; k++) s += p[(size_t)k * 5120];
    int i = j >> 8, t = j & 255;
    if (j < 4096) {
        int sg = t & 31, mg = t >> 5;
        atomicAdd(&WtT[(mg * 4 + (i >> 2)) * 128 + sg * 4 + (i & 3)], s);
    } else {
        int i2 = i - 16;
        int mW = t & 31, m2 = (t >> 5) * 4;
        atomicAdd(&WtW[mW * 32 + m2 + i2], s);
    }
}

// ------- cell_v_new = cell_v + ALPHA*(WtT - WtW @ cell_v)  [32,128] -------
__global__ __launch_bounds__(256) void cvnew_kern(
    const float* __restrict__ cv, const float* __restrict__ WtW,
    const float* __restrict__ WtT, float* __restrict__ cvn)
{
    int idx = blockIdx.x * 256 + threadIdx.x;   // 4096
    int s = idx & 127, m = idx >> 7;
    float g = WtT[idx];
#pragma unroll
    for (int j = 0; j < 32; j++) g -= WtW[m * 32 + j] * cv[j * 128 + s];
    cvn[idx] = cv[idx] + ALPHA_F * g;
}

// ------- E[m][pos*4+co] = sum_ci cvn[m][ci] * dw[ci][co][kh][kw] -------
__global__ __launch_bounds__(256) void emat_kern(
    const float* __restrict__ cvn, const float* __restrict__ dw, float* __restrict__ E)
{
    int idx = blockIdx.x * 256 + threadIdx.x;   // 2048
    int m = idx >> 6, j = idx & 63;
    int pos = j >> 2, co = j & 3;
    float s = 0.f;
    if (co < 3) {
        const float* cv = cvn + m * 128;        // uniform per 64-lane group -> s_loads
        for (int ci = 0; ci < 128; ci++)
            s += cv[ci] * dw[ci * 48 + co * 16 + pos];
    }
    E[idx] = s;
}

// ------- t64[pos][Tglobal][4] = (wmat[T,32] @ E[32,64]) pos-major (coalesced stores) -------
__global__ __launch_bounds__(256) void tread64_kern(
    const float* __restrict__ wmat, const float* __restrict__ E, float* __restrict__ t64)
{
    int t = blockIdx.x * 256 + threadIdx.x;
    float wv[32];
    const float4* wp = (const float4*)(wmat + (size_t)t * 32);
#pragma unroll
    for (int i = 0; i < 8; i++) {
        float4 v = wp[i];
        wv[4 * i] = v.x; wv[4 * i + 1] = v.y; wv[4 * i + 2] = v.z; wv[4 * i + 3] = v.w;
    }
    f32x4 acc[16];
#pragma unroll
    for (int i = 0; i < 16; i++)
#pragma unroll
        for (int r = 0; r < 4; r++) acc[i][r] = 0.f;
    const f32x4* E4 = (const f32x4*)E;
#pragma unroll 4
    for (int m = 0; m < 32; m++) {
        float wm = wv[m];
#pragma unroll
        for (int i = 0; i < 16; i++) {
            f32x4 e = E4[m * 16 + i];           // uniform -> s_load_dwordx4
#pragma unroll
            for (int r = 0; r < 4; r++) acc[i][r] += wm * e[r];
        }
    }
    f32x4* ob = (f32x4*)t64;
#pragma unroll
    for (int i = 0; i < 16; i++)
        ob[(size_t)i * TTOT + t] = acc[i];      // lane-consecutive 16B per pos-plane
}

// ------- decoder gather: dec1 = silu(sum of 4 taps from t64 + bias) -------
__global__ __launch_bounds__(256) void dec_gather_kern(
    const float* __restrict__ t64, const float* __restrict__ db, float* __restrict__ out)
{
    int g = blockIdx.x;                   // 512: b*64 + hb*8 + wb
    int wb = g & 7, hb = (g >> 3) & 7, b = g >> 6;
    int tx = threadIdx.x & 15, ty = threadIdx.x >> 4;
    int h2 = hb * 16 + ty, w2 = wb * 16 + tx;

    float mh[3], mw[3];
    int ihc[3], iwc[3];
#pragma unroll
    for (int a = 0; a < 3; a++) {
        int v = h2 - 1 + a;
        mh[a] = ((unsigned)v < 128u) ? 1.f : 0.f;
        ihc[a] = v < 0 ? 0 : (v > 127 ? 127 : v);
        v = w2 - 1 + a;
        mw[a] = ((unsigned)v < 128u) ? 1.f : 0.f;
        iwc[a] = v < 0 ? 0 : (v > 127 ? 127 : v);
    }
    float acc[2][2][3];
#pragma unroll
    for (int ph = 0; ph < 2; ph++)
#pragma unroll
        for (int pw = 0; pw < 2; pw++)
#pragma unroll
            for (int co = 0; co < 3; co++) acc[ph][pw][co] = db[co];

    const int RA[4] = {0, 1, 1, 2}, RP[4] = {0, 0, 1, 1}, RK[4] = {3, 1, 2, 0};
    size_t tokb = (size_t)b * 16384;
#pragma unroll
    for (int ri = 0; ri < 4; ri++)
#pragma unroll
        for (int cj = 0; cj < 4; cj++) {
            int a = RA[ri], c = RA[cj];
            float m = mh[a] * mw[c];
            size_t tok = tokb + (ihc[a] << 7) + iwc[c];
            int pos = RK[ri] * 4 + RK[cj];
            float4 v = *(const float4*)&t64[((size_t)pos * TTOT + tok) * 4];
            int ph = RP[ri], pw = RP[cj];
            acc[ph][pw][0] += m * v.x;
            acc[ph][pw][1] += m * v.y;
            acc[ph][pw][2] += m * v.z;
        }
    int h = 2 * h2, w = 2 * w2;
#pragma unroll
    for (int ph = 0; ph < 2; ph++)
#pragma unroll
        for (int co = 0; co < 3; co++) {
            float2 v = make_float2(silu_f(acc[ph][0][co]), silu_f(acc[ph][1][co]));
            *(float2*)&out[(size_t)b * 3 * 65536 + (size_t)co * 65536 + ((size_t)(h + ph) << 8) + w] = v;
        }
}

extern "C" void kernel_launch(void* const* d_in, const int* in_sizes, int n_in,
                              void* d_out, int out_size, void* d_ws, size_t ws_size,
                              hipStream_t stream)
{
    const float* x      = (const float*)d_in[0];
    const float* e0n_w1 = (const float*)d_in[1];
    const float* e0n_b1 = (const float*)d_in[2];
    const float* e0n_w2 = (const float*)d_in[3];
    const float* e0n_b2 = (const float*)d_in[4];
    const float* e0s_w1 = (const float*)d_in[5];
    const float* e0s_b1 = (const float*)d_in[6];
    const float* e0s_w2 = (const float*)d_in[7];
    const float* e0s_b2 = (const float*)d_in[8];
    const float* d0_dw  = (const float*)d_in[9];
    const float* d0_db  = (const float*)d_in[10];
    const float* d0_cw  = (const float*)d_in[11];
    const float* d0_cb  = (const float*)d_in[12];
    const float* cell_k = (const float*)d_in[13];
    const float* cell_v = (const float*)d_in[14];
    float* outp = (float*)d_out;

    char* ws = (char*)d_ws;
    char* a_s8             = ws;                              // 67 MB fp8
    __hip_bfloat16* t_star = (__hip_bfloat16*)(ws + 134217728);
    float* a_n    = (float*)(ws + 201326592);
    char* wt8     = (char*)(ws + 201326592);                  // reuses a_n after conv2n
    float* part   = (float*)(ws + 201850880);                 // 21 MB partials (a_n dead)
    float* Emat   = (float*)(ws + 224000000);                 // 8 KB
    float* wmat   = (float*)(ws + 243269632);
    float* WtW    = (float*)(ws + 260046848);
    float* WtT    = (float*)(ws + 260050944);
    float* cvn    = (float*)(ws + 260067328);
    float* t64    = (float*)(ws);               // reuse a_s8 region (dead after conv2s)
    float* dec1   = (float*)(ws + 67108864);

    // n-branch encoder; conv2n writes wmat directly (softmax fused)
    conv1_silu<16><<<2048, 256, 0, stream>>>(x, e0n_w1, e0n_b1, a_n);
    conv2n_fused<<<512, 256, 0, stream>>>(a_n, e0n_w2, e0n_b2, cell_k, wmat);
    // s-branch encoder: fp8 MFMA conv1 (co-split) -> fp8 MFMA implicit-GEMM conv2
    wprep_kern<<<144, 256, 0, stream>>>(e0s_w2, (int*)wt8);
    conv1s_mfma<<<8192, 256, 0, stream>>>(x, e0s_w1, e0s_b1, a_s8);
    conv2s_mfma<<<2048, 256, 0, stream>>>(a_s8, wt8, e0s_b2, t_star);
    // memcell
    hipMemsetAsync(WtW, 0, (1024 + 4096) * sizeof(float), stream);
    memcell_acc_kern<<<1024, 256, 0, stream>>>(wmat, t_star, part);
    memcell_reduce_kern<<<320, 256, 0, stream>>>(part, WtT, WtW);
    cvnew_kern<<<16, 256, 0, stream>>>(cell_v, WtW, WtT, cvn);
    // decoder: fold deconv weights through cvn, then gather from wmat-space (pos-major t64)
    emat_kern<<<8, 256, 0, stream>>>(cvn, d0_dw, Emat);
    tread64_kern<<<512, 256, 0, stream>>>(wmat, Emat, t64);
    dec_gather_kern<<<512, 256, 0, stream>>>(t64, d0_db, dec1);
    conv1_silu<3><<<2048, 256, 0, stream>>>(dec1, d0_cw, d0_cb, outp);
}